// Round 6
// baseline (73.689 us; speedup 1.0000x reference)
//
#include <hip/hip_runtime.h>

#define BATCH 524288
#define TPB 256
#define V 4   // samples per thread — amortize each U-row scalar fetch over 4 samples

typedef float vfloat16 __attribute__((ext_vector_type(16)));

// ---------------------------------------------------------------------------
// Kernel 1 (tiny): build the weight-only 16x16 unitary U into d_ws row-major:
// ws[j*32 + k] = Re U[j][k], ws[j*32 + 16 + k] = Im U[j][k].
// Thread k evolves basis state e_k (column k); writes transposed -> rows.
// ---------------------------------------------------------------------------
__global__ void qprep_kernel(const float* __restrict__ w, float* __restrict__ ws) {
    const int tid = threadIdx.x;
    if (tid >= 16) return;

    float stx[16], sty[16];
    #pragma unroll
    for (int i = 0; i < 16; i++) { stx[i] = 0.f; sty[i] = 0.f; }
    stx[tid] = 1.f;

    #pragma unroll
    for (int l = 0; l < 2; l++) {
        #pragma unroll
        for (int q = 0; q < 4; q++) {
            const float tz = 0.5f * w[l * 8 + q * 2 + 0];
            const float ty = 0.5f * w[l * 8 + q * 2 + 1];
            const float cz = __cosf(tz), sz = __sinf(tz);
            const float cy = __cosf(ty), sy = __sinf(ty);
            const int mask = 8 >> q;
            // RZ(t) = diag(e^{-it/2}, e^{+it/2})
            #pragma unroll
            for (int i = 0; i < 16; i++) {
                float ax = stx[i], ay = sty[i];
                if (i & mask) { stx[i] = ax * cz - ay * sz; sty[i] = ay * cz + ax * sz; }
                else          { stx[i] = ax * cz + ay * sz; sty[i] = ay * cz - ax * sz; }
            }
            // RY(t) = [[c,-s],[s,c]]
            #pragma unroll
            for (int i = 0; i < 16; i++) {
                if (!(i & mask)) {
                    float a0x = stx[i], a0y = sty[i];
                    float a1x = stx[i | mask], a1y = sty[i | mask];
                    stx[i]        = cy * a0x - sy * a1x;
                    sty[i]        = cy * a0y - sy * a1y;
                    stx[i | mask] = sy * a0x + cy * a1x;
                    sty[i | mask] = sy * a0y + cy * a1y;
                }
            }
        }
        // CNOT ring (0,1),(1,2),(2,3),(3,0); wire 0 is MSB (bit 3)
        #pragma unroll
        for (int e = 0; e < 4; e++) {
            const int cqs[4] = {0, 1, 2, 3};
            const int tqs[4] = {1, 2, 3, 0};
            const int cm = 8 >> cqs[e];
            const int tm = 8 >> tqs[e];
            #pragma unroll
            for (int i = 0; i < 16; i++) {
                if ((i & cm) && !(i & tm)) {
                    float t0x = stx[i], t0y = sty[i];
                    stx[i] = stx[i | tm]; sty[i] = sty[i | tm];
                    stx[i | tm] = t0x;    sty[i | tm] = t0y;
                }
            }
        }
    }
    #pragma unroll
    for (int j = 0; j < 16; j++) {
        ws[j * 32 + tid]      = stx[j];   // Re U[j][tid]
        ws[j * 32 + 16 + tid] = sty[j];   // Im U[j][tid]
    }
}

// ---------------------------------------------------------------------------
// Kernel 2 (hot): V=4 samples/thread. U rows pulled into SGPRs two rows at a
// time (4x s_load_dwordx16, ONE lgkmcnt drain per row-pair -> 8 drains/thread
// instead of 16), each row-pair reused across 4 samples. Inner loop is pure
// v_fma with SGPR operand. (256,2): 256-VGPR cap, zero spill risk for the
// ~120-reg live set (sv[4][16]=64 + z=16 + re/im=16 + trig/addr).
// ---------------------------------------------------------------------------
__global__ __launch_bounds__(TPB, 2) void qmain_kernel(const float* __restrict__ x,
                                                       const float* __restrict__ U,
                                                       float* __restrict__ out) {
    const int base = blockIdx.x * (TPB * V) + threadIdx.x;

    float sv[V][16];
    #pragma unroll
    for (int v = 0; v < V; v++) {
        const float4 xv = reinterpret_cast<const float4*>(x)[base + v * TPB];
        const float h0 = 0.5f * xv.x, h1 = 0.5f * xv.y, h2 = 0.5f * xv.z, h3 = 0.5f * xv.w;
        const float c0 = __cosf(h0), s0 = __sinf(h0);
        const float c1 = __cosf(h1), s1 = __sinf(h1);
        const float c2 = __cosf(h2), s2 = __sinf(h2);
        const float c3 = __cosf(h3), s3 = __sinf(h3);
        const float p01[4] = {c0 * c1, c0 * s1, s0 * c1, s0 * s1};
        const float p23[4] = {c2 * c3, c2 * s3, s2 * c3, s2 * s3};
        #pragma unroll
        for (int i = 0; i < 16; i++) sv[v][i] = p01[i >> 2] * p23[i & 3];
    }

    float z[V][4];
    #pragma unroll
    for (int v = 0; v < V; v++)
        #pragma unroll
        for (int i = 0; i < 4; i++) z[v][i] = 0.f;

    #pragma unroll
    for (int jj = 0; jj < 8; jj++) {
        const int j0 = 2 * jj, j1 = 2 * jj + 1;
        vfloat16 ur0, ui0, ur1, ui1;
        // Rows j0,j1 of U (Re+Im each), 128B row stride; wave-uniform -> SGPRs.
        // Single waitcnt per row-pair (SMEM returns may be out-of-order, so
        // partial lgkmcnt is unsafe — batch instead).
        asm volatile("s_load_dwordx16 %0, %4, 0x0\n\t"
                     "s_load_dwordx16 %1, %4, 0x40\n\t"
                     "s_load_dwordx16 %2, %4, 0x80\n\t"
                     "s_load_dwordx16 %3, %4, 0xC0\n\t"
                     "s_waitcnt lgkmcnt(0)"
                     : "=s"(ur0), "=s"(ui0), "=s"(ur1), "=s"(ui1)
                     : "s"(U + jj * 64));
        #pragma unroll
        for (int v = 0; v < V; v++) {
            float re0 = 0.f, im0 = 0.f, re1 = 0.f, im1 = 0.f;
            #pragma unroll
            for (int k = 0; k < 16; k++) {
                const float s = sv[v][k];
                re0 = fmaf(ur0[k], s, re0);
                im0 = fmaf(ui0[k], s, im0);
                re1 = fmaf(ur1[k], s, re1);
                im1 = fmaf(ui1[k], s, im1);
            }
            const float p0 = fmaf(re0, re0, im0 * im0);
            const float p1 = fmaf(re1, re1, im1 * im1);
            z[v][0] += ((j0 & 8) ? -p0 : p0) + ((j1 & 8) ? -p1 : p1);
            z[v][1] += ((j0 & 4) ? -p0 : p0) + ((j1 & 4) ? -p1 : p1);
            z[v][2] += ((j0 & 2) ? -p0 : p0) + ((j1 & 2) ? -p1 : p1);
            z[v][3] += ((j0 & 1) ? -p0 : p0) + ((j1 & 1) ? -p1 : p1);
        }
    }

    #pragma unroll
    for (int v = 0; v < V; v++) {
        reinterpret_cast<float4*>(out)[base + v * TPB] =
            make_float4(z[v][0], z[v][1], z[v][2], z[v][3]);
    }
}

extern "C" void kernel_launch(void* const* d_in, const int* in_sizes, int n_in,
                              void* d_out, int out_size, void* d_ws, size_t ws_size,
                              hipStream_t stream) {
    const float* x = (const float*)d_in[0];
    const float* w = (const float*)d_in[1];
    float* out = (float*)d_out;
    float* U = (float*)d_ws;  // 512 floats, 128B-row layout

    qprep_kernel<<<1, 64, 0, stream>>>(w, U);
    qmain_kernel<<<BATCH / (TPB * V), TPB, 0, stream>>>(x, U, out);  // 512 blocks
}